// Round 1
// baseline (408.326 us; speedup 1.0000x reference)
//
#include <hip/hip_runtime.h>
#include <hip/hip_bf16.h>

#define TT 8
#define CC 128
#define DD 64
#define HWp 9216
#define PP 8
#define NTILE 1152      // HWp / PP
#define XB_STRIDE 152   // bf16 elems per staged row (128 + 24 pad) = 304B
#define QKV_STRIDE 264  // bf16 elems per (t,p) row (256 + 8 pad) = 528B, 16B-aligned

typedef __attribute__((ext_vector_type(8))) short short8;
typedef __attribute__((ext_vector_type(4))) short short4v;
typedef __attribute__((ext_vector_type(4))) float floatx4;

__device__ __forceinline__ short f2bf(float f) {
    __hip_bfloat16 h = __float2bfloat16(f);
    return __builtin_bit_cast(short, h);
}
__device__ __forceinline__ float bf2f(short s) {
    unsigned u = ((unsigned)(unsigned short)s) << 16;
    return __builtin_bit_cast(float, u);
}

// block = 512 threads = 8 waves; LDS 38.7 KB -> 4 blocks/CU = 32 waves/CU.
// launch_bounds(512,8): 8 waves/EU -> VGPR capped at 64.
__global__ __launch_bounds__(512, 8) void ta_kernel(
    const float* __restrict__ x,
    const float* __restrict__ Wq, const float* __restrict__ bq,
    const float* __restrict__ Wk, const float* __restrict__ bk,
    const float* __restrict__ Wv, const float* __restrict__ bv,
    float* __restrict__ out)
{
    __shared__ short xb[16 * XB_STRIDE];            // 4864 B  (2 t x 8 p rows)
    __shared__ short qkv[TT * PP * QKV_STRIDE];     // 33792 B (row = t*8 + p)

    const int tid  = threadIdx.x;
    const int wave = tid >> 6;      // 0..7
    const int lane = tid & 63;
    const int quad = lane >> 4;
    const int l16  = lane & 15;

    // Bijective XCD swizzle: 4608 blocks, 8 XCDs, 576 contiguous work-items per
    // XCD so adjacent 8-pixel tiles (which share 64B lines) hit the same L2.
    const int orig = blockIdx.x;
    const int L    = (orig & 7) * (4 * NTILE / 8) + (orig >> 3);
    const int b    = L / NTILE;
    const int p0   = (L % NTILE) * PP;

    // ---- Preload weight A-fragments + biases into registers ----
    // Stacked f rows: [0,64) = Wq, [64,128) = Wk, [128,256) = Wv.
    // Wave w owns f-tiles 2w, 2w+1. A-frag (16x16x32): A[m=lane&15][k=quad*8+j].
    short8 wfrag[2][4];   // [tile][kchunk]
    float  bias[2][4];    // [tile][reg]
#pragma unroll
    for (int i = 0; i < 2; ++i) {
        const int f0  = (wave * 2 + i) * 16;
        const int row = f0 + l16;
        const float* wrow;
        if (row < DD)            wrow = Wq + row * CC;
        else if (row < 2 * DD)   wrow = Wk + (row - DD) * CC;
        else                     wrow = Wv + (row - 2 * DD) * CC;
#pragma unroll
        for (int kc = 0; kc < 4; ++kc) {
            const float* src = wrow + kc * 32 + quad * 8;
            short8 v;
#pragma unroll
            for (int j = 0; j < 8; ++j) v[j] = f2bf(src[j]);
            wfrag[i][kc] = v;
        }
        const int fb = f0 + quad * 4;   // rows this lane accumulates (D layout)
        const float* bsrc; int off;
        if (fb < DD)            { bsrc = bq; off = fb; }
        else if (fb < 2 * DD)   { bsrc = bk; off = fb - DD; }
        else                    { bsrc = bv; off = fb - 2 * DD; }
#pragma unroll
        for (int r = 0; r < 4; ++r) bias[i][r] = bsrc[off + r];
    }

    // ---- Projection: t-pair per iteration. B columns = (t_off 2) x (p 8). ----
    // 512 threads cover 2t x 128c x 8p in one float4 each; prefetch next pair.
    const int c0   = tid >> 2;            // 0..127
    const int toff = (tid >> 1) & 1;      // t within pair
    const int p4   = (tid & 1) * 4;       // 0 or 4
    const float* xsrc0 = x + ((size_t)(b * TT + toff) * CC + c0) * HWp + p0 + p4;

    float4 cur = *(const float4*)xsrc0;
    for (int tp = 0; tp < 4; ++tp) {
        float4 nxt = cur;
        if (tp < 3)
            nxt = *(const float4*)(xsrc0 + (size_t)(tp + 1) * 2 * CC * HWp);  // in flight

        __syncthreads();   // xb from previous iteration fully consumed
        const int xrow = toff * PP + p4;
        xb[(xrow + 0) * XB_STRIDE + c0] = f2bf(cur.x);
        xb[(xrow + 1) * XB_STRIDE + c0] = f2bf(cur.y);
        xb[(xrow + 2) * XB_STRIDE + c0] = f2bf(cur.z);
        xb[(xrow + 3) * XB_STRIDE + c0] = f2bf(cur.w);
        __syncthreads();

        // D = A(W: f x c) * B(x: c x (t,p)). B-frag: B[k=quad*8+j][n=lane&15],
        // column n = (toff = n>>3, p = n&7); contiguous 8 bf16 -> ds_read_b128.
        floatx4 acc[2];
#pragma unroll
        for (int i = 0; i < 2; ++i)
#pragma unroll
            for (int r = 0; r < 4; ++r) acc[i][r] = 0.f;
#pragma unroll
        for (int kc = 0; kc < 4; ++kc) {
            short8 xf = *(const short8*)&xb[l16 * XB_STRIDE + kc * 32 + quad * 8];
            acc[0] = __builtin_amdgcn_mfma_f32_16x16x32_bf16(wfrag[0][kc], xf, acc[0], 0, 0, 0);
            acc[1] = __builtin_amdgcn_mfma_f32_16x16x32_bf16(wfrag[1][kc], xf, acc[1], 0, 0, 0);
        }
        // D layout: col(n) = lane&15 -> qkv row tp*16 + l16 (= (t*8+p));
        // row(m=f) = quad*4 + r.
#pragma unroll
        for (int i = 0; i < 2; ++i) {
            const int f0 = (wave * 2 + i) * 16 + quad * 4;
            short4v o;
#pragma unroll
            for (int r = 0; r < 4; ++r) o[r] = f2bf(acc[i][r] + bias[i][r]);
            *(short4v*)&qkv[(tp * 16 + l16) * QKV_STRIDE + f0] = o;
        }
        cur = nxt;
    }
    __syncthreads();

    // ---- Attention: 64 threads/pixel = (tq = wave) x (d/e-slice 8), fp32 VALU.
    // No redundant score work: each thread does 8 of 64 d's, shfl_xor-reduced.
    {
        const int p   = tid & 7;          // pixel
        const int dsl = (tid >> 3) & 7;   // d-slice (scores) / e-slice (PV)
        const int tq  = wave;

        const short* prow = &qkv[p * QKV_STRIDE];   // row (s,p) = prow + s*8*QKV_STRIDE

        float qv[8];
        {
            short8 v = *(const short8*)(prow + (tq * PP) * QKV_STRIDE + dsl * 8);
#pragma unroll
            for (int j = 0; j < 8; ++j) qv[j] = bf2f(v[j]);
        }
        float sc[TT];
#pragma unroll
        for (int s = 0; s < TT; ++s) {
            short8 v = *(const short8*)(prow + (s * PP) * QKV_STRIDE + DD + dsl * 8);
            float a = 0.f;
#pragma unroll
            for (int j = 0; j < 8; ++j) a = fmaf(qv[j], bf2f(v[j]), a);
            sc[s] = a;
        }
        // reduce partial dots across the 8 d-slice lanes (lane bits 3..5)
#pragma unroll
        for (int m = 8; m <= 32; m <<= 1)
#pragma unroll
            for (int s = 0; s < TT; ++s) sc[s] += __shfl_xor(sc[s], m, 64);

        float mx = sc[0];
#pragma unroll
        for (int s = 1; s < TT; ++s) mx = fmaxf(mx, sc[s]);
        float sum = 0.f;
#pragma unroll
        for (int s = 0; s < TT; ++s) {
            float e = __expf((sc[s] - mx) * 0.125f);   // fold 1/sqrt(64) into exp arg
            sc[s] = e; sum += e;
        }
        const float inv = 1.f / sum;
#pragma unroll
        for (int s = 0; s < TT; ++s) sc[s] *= inv;

        // PV: this thread owns e in [dsl*16, dsl*16+16)
        float o[16];
#pragma unroll
        for (int j = 0; j < 16; ++j) o[j] = 0.f;
#pragma unroll
        for (int s = 0; s < TT; ++s) {
            const short* vr = prow + (s * PP) * QKV_STRIDE + 2 * DD + dsl * 16;
            short8 v0 = *(const short8*)vr;
            short8 v1 = *(const short8*)(vr + 8);
            const float a = sc[s];
#pragma unroll
            for (int j = 0; j < 8; ++j) {
                o[j]     = fmaf(a, bf2f(v0[j]), o[j]);
                o[8 + j] = fmaf(a, bf2f(v1[j]), o[8 + j]);
            }
        }
        // out[b][tq][e][hw]; lanes 0..7 = consecutive pixels -> 32B segments,
        // adjacent tiles on same XCD merge lines in L2.
        float* op = out + ((size_t)((b * TT + tq) * CC + dsl * 16)) * HWp + p0 + p;
#pragma unroll
        for (int e = 0; e < 16; ++e) op[(size_t)e * HWp] = o[e];
    }
}

extern "C" void kernel_launch(void* const* d_in, const int* in_sizes, int n_in,
                              void* d_out, int out_size, void* d_ws, size_t ws_size,
                              hipStream_t stream) {
    const float* x  = (const float*)d_in[0];
    const float* Wq = (const float*)d_in[1];
    const float* bq = (const float*)d_in[2];
    const float* Wk = (const float*)d_in[3];
    const float* bk = (const float*)d_in[4];
    const float* Wv = (const float*)d_in[5];
    const float* bv = (const float*)d_in[6];
    float* out = (float*)d_out;

    const int blocks = 4 * NTILE;   // B=4 x 1152 pixel-tiles = 4608
    ta_kernel<<<blocks, 512, 0, stream>>>(x, Wq, bq, Wk, bk, Wv, bv, out);
}

// Round 2
// 332.049 us; speedup vs baseline: 1.2297x; 1.2297x over previous
//
#include <hip/hip_runtime.h>
#include <hip/hip_bf16.h>

#define TT 8
#define CC 128
#define DD 64
#define HWp 9216
#define PP 16
#define NTILE 576       // HWp / PP
#define XB_STRIDE 152   // bf16 elems per staged row (128 + 24 pad) = 304B
#define QKV_STRIDE 264  // bf16 elems per (t,p) row (256 + 8 pad) = 528B, 16B-aligned

typedef __attribute__((ext_vector_type(8))) short short8;
typedef __attribute__((ext_vector_type(4))) short short4v;
typedef __attribute__((ext_vector_type(4))) float floatx4;
typedef __attribute__((ext_vector_type(4))) unsigned uint4v;

__device__ __forceinline__ short f2bf(float f) {
    __hip_bfloat16 h = __float2bfloat16(f);
    return __builtin_bit_cast(short, h);
}
__device__ __forceinline__ float u2f(unsigned u) {
    return __builtin_bit_cast(float, u);
}
// short8 (8 bf16) -> 8 floats, 1 VALU op per element (shift / mask).
__device__ __forceinline__ void bf8_to_f(short8 v, float* f) {
    uint4v u = __builtin_bit_cast(uint4v, v);
#pragma unroll
    for (int i = 0; i < 4; ++i) {
        f[2 * i]     = u2f(u[i] << 16);
        f[2 * i + 1] = u2f(u[i] & 0xffff0000u);
    }
}

// block = 512 threads = 8 waves; LDS ~77KB -> 2 blocks/CU (LDS-limited).
__global__ __launch_bounds__(512, 4) void ta_kernel(
    const float* __restrict__ x,
    const float* __restrict__ Wq, const float* __restrict__ bq,
    const float* __restrict__ Wk, const float* __restrict__ bk,
    const float* __restrict__ Wv, const float* __restrict__ bv,
    float* __restrict__ out)
{
    __shared__ short xb[32 * XB_STRIDE];            // 9728 B (2 t x 16 p rows)
    __shared__ short qkv[TT * PP * QKV_STRIDE];     // 67584 B (row = t*16 + p)

    const int tid  = threadIdx.x;
    const int wave = tid >> 6;      // 0..7
    const int lane = tid & 63;
    const int quad = lane >> 4;
    const int l16  = lane & 15;

    const int blk = blockIdx.x;
    const int b   = blk / NTILE;
    const int p0  = (blk % NTILE) * PP;

    // ---- Preload weight A-fragments + biases into registers ----
    // Stacked f rows: [0,64) = Wq, [64,128) = Wk, [128,256) = Wv.
    // Wave w owns f-tiles 2w, 2w+1. A-frag (16x16x32): A[m=lane&15][k=quad*8+j].
    short8 wfrag[2][4];   // [tile][kchunk]
    float  bias[2][4];    // [tile][reg]
#pragma unroll
    for (int i = 0; i < 2; ++i) {
        const int f0  = (wave * 2 + i) * 16;
        const int row = f0 + l16;
        const float* wrow;
        if (row < DD)            wrow = Wq + row * CC;
        else if (row < 2 * DD)   wrow = Wk + (row - DD) * CC;
        else                     wrow = Wv + (row - 2 * DD) * CC;
#pragma unroll
        for (int kc = 0; kc < 4; ++kc) {
            const float* src = wrow + kc * 32 + quad * 8;
            short8 v;
#pragma unroll
            for (int j = 0; j < 8; ++j) v[j] = f2bf(src[j]);
            wfrag[i][kc] = v;
        }
        const int fb = f0 + quad * 4;   // rows this lane accumulates (D layout)
        const float* bsrc; int off;
        if (fb < DD)            { bsrc = bq; off = fb; }
        else if (fb < 2 * DD)   { bsrc = bk; off = fb - DD; }
        else                    { bsrc = bv; off = fb - 2 * DD; }
#pragma unroll
        for (int r = 0; r < 4; ++r) bias[i][r] = bsrc[off + r];
    }

    // ---- Projection: t-PAIR per iteration (halves barrier rounds). ----
    // 512 threads: each loads one float4 (c0, p4..p4+3) for BOTH t's of the pair.
    const int c0 = tid >> 2;            // 0..127
    const int p4 = (tid & 3) * 4;       // 0,4,8,12
    const float* xsrc = x + ((size_t)(b * TT) * CC + c0) * HWp + p0 + p4;

    float4 cur0 = *(const float4*)xsrc;
    float4 cur1 = *(const float4*)(xsrc + (size_t)CC * HWp);
    for (int tp = 0; tp < 4; ++tp) {
        float4 nxt0 = cur0, nxt1 = cur1;
        if (tp < 3) {
            nxt0 = *(const float4*)(xsrc + (size_t)(2 * tp + 2) * CC * HWp);
            nxt1 = *(const float4*)(xsrc + (size_t)(2 * tp + 3) * CC * HWp);
        }

        __syncthreads();   // xb from previous iteration fully consumed
        xb[(p4 + 0) * XB_STRIDE + c0] = f2bf(cur0.x);
        xb[(p4 + 1) * XB_STRIDE + c0] = f2bf(cur0.y);
        xb[(p4 + 2) * XB_STRIDE + c0] = f2bf(cur0.z);
        xb[(p4 + 3) * XB_STRIDE + c0] = f2bf(cur0.w);
        xb[(16 + p4 + 0) * XB_STRIDE + c0] = f2bf(cur1.x);
        xb[(16 + p4 + 1) * XB_STRIDE + c0] = f2bf(cur1.y);
        xb[(16 + p4 + 2) * XB_STRIDE + c0] = f2bf(cur1.z);
        xb[(16 + p4 + 3) * XB_STRIDE + c0] = f2bf(cur1.w);
        __syncthreads();

        // D = A(W: f x c) * B(x: c x p), two B-tiles (t-even, t-odd).
        // B-frag: B[k=quad*8+j][n=lane&15], contiguous 8 bf16 (ds_read_b128).
        floatx4 acc[2][2];   // [t-tile][w-tile]
#pragma unroll
        for (int tt = 0; tt < 2; ++tt)
#pragma unroll
            for (int i = 0; i < 2; ++i)
#pragma unroll
                for (int r = 0; r < 4; ++r) acc[tt][i][r] = 0.f;
#pragma unroll
        for (int kc = 0; kc < 4; ++kc) {
            short8 xf0 = *(const short8*)&xb[l16 * XB_STRIDE + kc * 32 + quad * 8];
            short8 xf1 = *(const short8*)&xb[(16 + l16) * XB_STRIDE + kc * 32 + quad * 8];
            acc[0][0] = __builtin_amdgcn_mfma_f32_16x16x32_bf16(wfrag[0][kc], xf0, acc[0][0], 0, 0, 0);
            acc[0][1] = __builtin_amdgcn_mfma_f32_16x16x32_bf16(wfrag[1][kc], xf0, acc[0][1], 0, 0, 0);
            acc[1][0] = __builtin_amdgcn_mfma_f32_16x16x32_bf16(wfrag[0][kc], xf1, acc[1][0], 0, 0, 0);
            acc[1][1] = __builtin_amdgcn_mfma_f32_16x16x32_bf16(wfrag[1][kc], xf1, acc[1][1], 0, 0, 0);
        }
        // D layout: col(n=p) = lane&15, row(m=f) = quad*4 + r.
#pragma unroll
        for (int tt = 0; tt < 2; ++tt)
#pragma unroll
            for (int i = 0; i < 2; ++i) {
                const int f0 = (wave * 2 + i) * 16 + quad * 4;
                short4v o;
#pragma unroll
                for (int r = 0; r < 4; ++r) o[r] = f2bf(acc[tt][i][r] + bias[i][r]);
                *(short4v*)&qkv[((2 * tp + tt) * PP + l16) * QKV_STRIDE + f0] = o;
            }
        cur0 = nxt0; cur1 = nxt1;
    }
    __syncthreads();

    // ---- Attention: 64 threads/pixel-paired as (tq = wave) x (quad = slice).
    // Scores: each thread does 16 of 64 d's, shfl_xor-reduced across quads.
    {
        const int p  = l16;
        const int tq = wave;

        const short* prow = &qkv[p * QKV_STRIDE];   // row (s,p) = prow + s*16*QKV_STRIDE

        float qv[16];
        {
            const short* q8 = prow + (tq * PP) * QKV_STRIDE + quad * 16;
            bf8_to_f(*(const short8*)q8, qv);
            bf8_to_f(*(const short8*)(q8 + 8), qv + 8);
        }
        float sc[TT];
#pragma unroll
        for (int s = 0; s < TT; ++s) {
            const short* k8 = prow + (s * PP) * QKV_STRIDE + DD + quad * 16;
            float kv[16];
            bf8_to_f(*(const short8*)k8, kv);
            bf8_to_f(*(const short8*)(k8 + 8), kv + 8);
            float a = 0.f;
#pragma unroll
            for (int j = 0; j < 16; ++j) a = fmaf(qv[j], kv[j], a);
            sc[s] = a;
        }
        // reduce partial dots across the 4 quads (lane bits 4,5)
#pragma unroll
        for (int m = 16; m <= 32; m <<= 1)
#pragma unroll
            for (int s = 0; s < TT; ++s) sc[s] += __shfl_xor(sc[s], m, 64);

        float mx = sc[0];
#pragma unroll
        for (int s = 1; s < TT; ++s) mx = fmaxf(mx, sc[s]);
        float sum = 0.f;
#pragma unroll
        for (int s = 0; s < TT; ++s) {
            float e = __expf((sc[s] - mx) * 0.125f);   // fold 1/sqrt(64) into exp arg
            sc[s] = e; sum += e;
        }
        const float inv = 1.f / sum;
#pragma unroll
        for (int s = 0; s < TT; ++s) sc[s] *= inv;

        // PV: thread owns e = k*32 + quad*8 + j (k=0..3, j=0..7) — quad-interleaved
        // chunks spread the 4 quads across LDS banks (no +16-dword phase collision).
        float o[32];
#pragma unroll
        for (int j = 0; j < 32; ++j) o[j] = 0.f;
#pragma unroll
        for (int s = 0; s < TT; ++s) {
            const short* vrow = prow + (s * PP) * QKV_STRIDE + 2 * DD + quad * 8;
            const float a = sc[s];
#pragma unroll
            for (int k = 0; k < 4; ++k) {
                float vv[8];
                bf8_to_f(*(const short8*)(vrow + k * 32), vv);
#pragma unroll
                for (int j = 0; j < 8; ++j) o[k * 8 + j] = fmaf(a, vv[j], o[k * 8 + j]);
            }
        }
        // out[b][tq][e][hw]; lanes 0..15 = consecutive pixels -> full 64B lines
        float* op = out + ((size_t)((b * TT + tq) * CC + quad * 8)) * HWp + p0 + p;
#pragma unroll
        for (int k = 0; k < 4; ++k)
#pragma unroll
            for (int j = 0; j < 8; ++j)
                op[(size_t)(k * 32 + j) * HWp] = o[k * 8 + j];
    }
}

extern "C" void kernel_launch(void* const* d_in, const int* in_sizes, int n_in,
                              void* d_out, int out_size, void* d_ws, size_t ws_size,
                              hipStream_t stream) {
    const float* x  = (const float*)d_in[0];
    const float* Wq = (const float*)d_in[1];
    const float* bq = (const float*)d_in[2];
    const float* Wk = (const float*)d_in[3];
    const float* bk = (const float*)d_in[4];
    const float* Wv = (const float*)d_in[5];
    const float* bv = (const float*)d_in[6];
    float* out = (float*)d_out;

    const int blocks = 4 * NTILE;   // B=4 x 576 pixel-tiles = 2304
    ta_kernel<<<blocks, 512, 0, stream>>>(x, Wq, bq, Wk, bk, Wv, bv, out);
}